// Round 10
// baseline (732.072 us; speedup 1.0000x reference)
//
#include <hip/hip_runtime.h>
#include <math.h>

#define NDIM 256
#define VOL  (NDIM*NDIM*NDIM)      // 16777216 elements per batch-channel volume
#define NB   128                    // kept bins 0..127; label 128 is dropped
#define KZ   128                    // stored kz extent per half-volume.
                                    // kz=128 (Nyquist) has |fz|=0.5 -> label>=128
                                    // -> dropped by the reference; never stored.
#define HVOL (NDIM*NDIM*KZ)         // 8388608 float2 = 64 MB per half-volume
#define PADC 10                     // x-pass tile: 8 kz cols padded to 10 (16B-aligned,
                                    // 2-way-max bank aliasing = free)

// base-4 digit reversal of an 8-bit index (involution)
__device__ __forceinline__ int dr4(int x) {
    int b = (int)(__brev((unsigned)x) >> 24);
    return ((b >> 1) & 0x55) | ((b << 1) & 0xAA);
}
__device__ __forceinline__ float2 cmul(float2 a, float2 b) {
    return make_float2(a.x * b.x - a.y * b.y, a.x * b.y + a.y * b.x);
}
__device__ __forceinline__ float2 cadd(float2 a, float2 b){ return make_float2(a.x+b.x, a.y+b.y); }
__device__ __forceinline__ float2 csub(float2 a, float2 b){ return make_float2(a.x-b.x, a.y-b.y); }
__device__ __forceinline__ float2 cmuli_neg(float2 a){ return make_float2(a.y, -a.x); }  // -i*a
__device__ __forceinline__ float2 cmuli_pos(float2 a){ return make_float2(-a.y, a.x); }  // +i*a

// ---------------------------------------------------------------------------
// Pass 1: pack (ref + i*pred), radix-4 Stockham FFT along z (wave-private,
// natural order), then Hermitian UNPACK in LDS: the conjugate partner along
// z is in the same line, so F1z = (Z(kz)+conj(Z(-kz)))/2 and
// F2z = (Z(kz)-conj(Z(-kz)))/(2i) are computed here and written as two
// explicit half-spectra A1, A2 with kz in [0,127]. This removes the need
// for any conjugate pairing later: shell weight becomes kz-only
// (w=1 at kz=0, w=2 for kz in [1,127]); the kz=128 plane is label>=128 ->
// dropped by the reference, so it is never written.
// ---------------------------------------------------------------------------
__global__ __launch_bounds__(256) void fftz_split(const float* __restrict__ re_in,
                                                  const float* __restrict__ im_in,
                                                  float2* __restrict__ A1,
                                                  float2* __restrict__ A2)
{
    __shared__ float2 buf[4][2][NDIM];   // 16 KB, per-wave double buffer
    const int t = threadIdx.x;
    const int w = t >> 6, j = t & 63;
    const int L = blockIdx.x * 4 + w;    // line id in [0, 65536)
    const float* rp = re_in + (size_t)L * NDIM;
    const float* ip = im_in + (size_t)L * NDIM;

    float2 v0 = make_float2(rp[j      ], ip[j      ]);
    float2 v1 = make_float2(rp[j +  64], ip[j +  64]);
    float2 v2 = make_float2(rp[j + 128], ip[j + 128]);
    float2 v3 = make_float2(rp[j + 192], ip[j + 192]);

    // stage 0 (Ns=1, twiddle = 1): write at 4j + r
    {
        float2 t0=cadd(v0,v2), t1=csub(v0,v2), t2=cadd(v1,v3), t3=csub(v1,v3);
        buf[w][0][4*j    ] = cadd(t0, t2);
        buf[w][0][4*j + 1] = cadd(t1, cmuli_neg(t3));
        buf[w][0][4*j + 2] = csub(t0, t2);
        buf[w][0][4*j + 3] = cadd(t1, cmuli_pos(t3));
    }
    __builtin_amdgcn_sched_barrier(0);

    int p = 0;
    #pragma unroll
    for (int stage = 1; stage <= 2; ++stage) {
        const int Ns = (stage == 1) ? 4 : 16;
        const int jm = j & (Ns - 1);
        float2 a0 = buf[w][p][j      ];
        float2 a1 = buf[w][p][j +  64];
        float2 a2 = buf[w][p][j + 128];
        float2 a3 = buf[w][p][j + 192];
        float sn, cs;
        __sincosf(-(float)(2.0 * M_PI) * (float)jm / (float)(4 * Ns), &sn, &cs);
        float2 w1 = make_float2(cs, sn);
        float2 w2 = cmul(w1, w1);
        float2 w3 = cmul(w2, w1);
        a1 = cmul(a1, w1); a2 = cmul(a2, w2); a3 = cmul(a3, w3);
        float2 t0=cadd(a0,a2), t1=csub(a0,a2), t2=cadd(a1,a3), t3=csub(a1,a3);
        const int idxD = (j / Ns) * (4 * Ns) + jm;
        buf[w][p^1][idxD         ] = cadd(t0, t2);
        buf[w][p^1][idxD +     Ns] = cadd(t1, cmuli_neg(t3));
        buf[w][p^1][idxD + 2 * Ns] = csub(t0, t2);
        buf[w][p^1][idxD + 3 * Ns] = cadd(t1, cmuli_pos(t3));
        p ^= 1;
        __builtin_amdgcn_sched_barrier(0);
    }

    // stage 3 (Ns=64): idxD = j, write to LDS (not global)
    {
        float2 a0 = buf[w][p][j      ];
        float2 a1 = buf[w][p][j +  64];
        float2 a2 = buf[w][p][j + 128];
        float2 a3 = buf[w][p][j + 192];
        float sn, cs;
        __sincosf(-(float)(2.0 * M_PI) * (float)j / 256.0f, &sn, &cs);
        float2 w1 = make_float2(cs, sn);
        float2 w2 = cmul(w1, w1);
        float2 w3 = cmul(w2, w1);
        a1 = cmul(a1, w1); a2 = cmul(a2, w2); a3 = cmul(a3, w3);
        float2 t0=cadd(a0,a2), t1=csub(a0,a2), t2=cadd(a1,a3), t3=csub(a1,a3);
        float2* bd = buf[w][p^1];
        bd[j      ] = cadd(t0, t2);
        bd[j +  64] = cadd(t1, cmuli_neg(t3));
        bd[j + 128] = csub(t0, t2);
        bd[j + 192] = cadd(t1, cmuli_pos(t3));
    }
    __builtin_amdgcn_sched_barrier(0);

    // Hermitian unpack: kz in [0,127] (thread j handles kz = j and j+64)
    const float2* Zf = buf[w][p^1];
    float2* o1 = A1 + (size_t)L * KZ;
    float2* o2 = A2 + (size_t)L * KZ;
    #pragma unroll
    for (int r = 0; r < 2; ++r) {
        const int kz = j + 64 * r;
        float2 a = Zf[kz];
        float2 b = Zf[(NDIM - kz) & 255];
        o1[kz] = make_float2(0.5f * (a.x + b.x), 0.5f * (a.y - b.y));
        o2[kz] = make_float2(0.5f * (a.y + b.y), 0.5f * (b.x - a.x));
    }
}

// ---------------------------------------------------------------------------
// Pass 2 (y): in-place radix-4 DIF FFT along a strided axis.
// Tile 256 (FFT dim) x 16 (contiguous kz), ld = 18 float2. Output
// digit-reversed along the axis. Generalized chunk indexing:
// o = bid >> chunkShift (outer), c = bid & chunkMask (16-wide z chunk).
// Half-volume y-pass: lineStride=128, outerStride=32768, 8 chunks, grid 2048.
// ---------------------------------------------------------------------------
__global__ __launch_bounds__(256) void fft_strided(float2* __restrict__ A,
                                                   int lineStride, long long outerStride,
                                                   int chunkMask, int chunkShift)
{
    __shared__ __align__(16) float2 tile[NDIM * 18];   // 36.9 KB
    __shared__ float2 tw[NDIM];          // 2 KB: tw[k] = exp(-2*pi*i*k/256)
    const int t = threadIdx.x;
    {
        float sn, cs;
        __sincosf(-(float)(2.0 * M_PI) * (float)t / 256.0f, &sn, &cs);
        tw[t] = make_float2(cs, sn);
    }
    const int l4 = t & 7, u8 = t >> 3;   // load layout: 8 float4 per tile row
    const int o = blockIdx.x >> chunkShift, c = blockIdx.x & chunkMask;
    const long long base = (long long)o * outerStride + c * 16;

    #pragma unroll
    for (int it = 0; it < 8; ++it) {
        int pos = u8 + it * 32;
        const float4 d = *(const float4*)&A[base + (long long)pos * lineStride + 2 * l4];
        tile[pos * 18 + 2 * l4    ] = make_float2(d.x, d.y);
        tile[pos * 18 + 2 * l4 + 1] = make_float2(d.z, d.w);
    }
    __syncthreads();

    const int l = t & 15, u = t >> 4;
    #pragma unroll
    for (int ls = 6; ls >= 0; ls -= 2) {           // s = 64, 16, 4, 1
        const int s = 1 << ls;
        #pragma unroll
        for (int it = 0; it < 4; ++it) {
            int m  = u + it * 16;                  // butterfly id in [0,64)
            int jm = m & (s - 1);
            int bidx = ((m >> ls) << (ls + 2)) + jm;
            float2 a  = tile[(bidx        ) * 18 + l];
            float2 b  = tile[(bidx +     s) * 18 + l];
            float2 cc = tile[(bidx + 2 * s) * 18 + l];
            float2 d  = tile[(bidx + 3 * s) * 18 + l];
            float2 t0=cadd(a,cc), t1=csub(a,cc), t2=cadd(b,d), t3=csub(b,d);
            float2 y0 = cadd(t0, t2);
            float2 y1 = cadd(t1, cmuli_neg(t3));
            float2 y2 = csub(t0, t2);
            float2 y3 = cadd(t1, cmuli_pos(t3));
            int k1 = jm << (6 - ls);               // 256/(4s) multiplier
            y1 = cmul(y1, tw[k1]);
            y2 = cmul(y2, tw[2 * k1]);
            y3 = cmul(y3, tw[3 * k1]);
            tile[(bidx        ) * 18 + l] = y0;
            tile[(bidx +     s) * 18 + l] = y1;
            tile[(bidx + 2 * s) * 18 + l] = y2;
            tile[(bidx + 3 * s) * 18 + l] = y3;
        }
        __syncthreads();
    }

    #pragma unroll
    for (int it = 0; it < 8; ++it) {
        int pos = u8 + it * 32;
        float2 e0 = tile[pos * 18 + 2 * l4], e1 = tile[pos * 18 + 2 * l4 + 1];
        *(float4*)&A[base + (long long)pos * lineStride + 2 * l4] =
            make_float4(e0.x, e0.y, e1.x, e1.y);
    }
}

// ---------------------------------------------------------------------------
// Pass 3: x-FFT on BOTH half-volumes + FUSED shell reduction.
// Block = (y' slab, 8-kz chunk): loads 256x x 8kz tiles from A1 and A2
// (32 KB useful), radix-4 DIF butterflies on both, then reduces in the
// epilogue: kx = dr4(pos), ky = dr4(o), kz natural; label = floor(sqrt(c2)),
// weight 1 at kz=0 else 2. NO global write-back of the FFT result — the
// spectrum is consumed in LDS. This deletes the old standalone reduce pass
// (94 us, stuck at ~1.4 TB/s across 9 structural variants) and the x-pass
// 64 MB write.
// ---------------------------------------------------------------------------
__global__ __launch_bounds__(256) void fftx_reduce(const float2* __restrict__ A1,
                                                   const float2* __restrict__ A2,
                                                   float* __restrict__ bins)
{
    __shared__ __align__(16) float2 t1[NDIM * PADC]; // 20 KB
    __shared__ __align__(16) float2 t2[NDIM * PADC]; // 20 KB
    __shared__ float2 tw[NDIM];                      // 2 KB
    __shared__ float bs[4][3 * NB];                  // 6 KB: per-wave histograms
    const int t = threadIdx.x;
    {
        float sn, cs;
        __sincosf(-(float)(2.0 * M_PI) * (float)t / 256.0f, &sn, &cs);
        tw[t] = make_float2(cs, sn);
    }
    for (int i = t; i < 4 * 3 * NB; i += 256) ((float*)bs)[i] = 0.f;

    const int o   = blockIdx.x >> 4;     // y' (storage index after y-pass)
    const int c   = blockIdx.x & 15;     // kz chunk
    const int kz0 = c * 8;
    const size_t base = (size_t)o * KZ + kz0;

    // load both tiles: thread (q = t&3, x = t>>2 + 64*it), float4 = 2 kz
    const int q = t & 3, xr = t >> 2;
    #pragma unroll
    for (int it = 0; it < 4; ++it) {
        int x = xr + it * 64;
        size_t g = base + (size_t)x * (NDIM * KZ) + 2 * q;
        float4 d1 = *(const float4*)&A1[g];
        float4 d2 = *(const float4*)&A2[g];
        *(float4*)&t1[x * PADC + 2 * q] = d1;
        *(float4*)&t2[x * PADC + 2 * q] = d2;
    }
    __syncthreads();

    // butterflies: l = kz lane [0,8), u = group [0,32), 2 iters -> 64 bflies
    const int l = t & 7, u = t >> 3;
    #pragma unroll
    for (int ls = 6; ls >= 0; ls -= 2) {           // s = 64, 16, 4, 1
        const int s = 1 << ls;
        #pragma unroll
        for (int it = 0; it < 2; ++it) {
            int m  = u + it * 32;
            int jm = m & (s - 1);
            int bidx = ((m >> ls) << (ls + 2)) + jm;
            int k1 = jm << (6 - ls);
            {
                float2 a  = t1[(bidx        ) * PADC + l];
                float2 b  = t1[(bidx +     s) * PADC + l];
                float2 cc = t1[(bidx + 2 * s) * PADC + l];
                float2 d  = t1[(bidx + 3 * s) * PADC + l];
                float2 t0=cadd(a,cc), u1=csub(a,cc), t2_=cadd(b,d), t3=csub(b,d);
                t1[(bidx        ) * PADC + l] = cadd(t0, t2_);
                t1[(bidx +     s) * PADC + l] = cmul(cadd(u1, cmuli_neg(t3)), tw[k1]);
                t1[(bidx + 2 * s) * PADC + l] = cmul(csub(t0, t2_), tw[2 * k1]);
                t1[(bidx + 3 * s) * PADC + l] = cmul(cadd(u1, cmuli_pos(t3)), tw[3 * k1]);
            }
            {
                float2 a  = t2[(bidx        ) * PADC + l];
                float2 b  = t2[(bidx +     s) * PADC + l];
                float2 cc = t2[(bidx + 2 * s) * PADC + l];
                float2 d  = t2[(bidx + 3 * s) * PADC + l];
                float2 t0=cadd(a,cc), u1=csub(a,cc), t2_=cadd(b,d), t3=csub(b,d);
                t2[(bidx        ) * PADC + l] = cadd(t0, t2_);
                t2[(bidx +     s) * PADC + l] = cmul(cadd(u1, cmuli_neg(t3)), tw[k1]);
                t2[(bidx + 2 * s) * PADC + l] = cmul(csub(t0, t2_), tw[2 * k1]);
                t2[(bidx + 3 * s) * PADC + l] = cmul(cadd(u1, cmuli_pos(t3)), tw[3 * k1]);
            }
        }
        __syncthreads();
    }

    // fused shell reduction epilogue
    const int ky = dr4(o);
    const int ay = (ky <= 128) ? ky : NDIM - ky;
    const int wv  = t >> 6;
    const int kzl = t & 7, pr = t >> 3;
    const int kz  = kz0 + kzl;
    const float g = (kz == 0) ? 1.f : 2.f;
    const int ayz2 = ay * ay + kz * kz;
    #pragma unroll
    for (int it = 0; it < 8; ++it) {
        int pos = pr + it * 32;
        int kx = dr4(pos);
        int ax = (kx <= 128) ? kx : NDIM - kx;
        int c2 = ax * ax + ayz2;
        if (c2 < NB * NB) {                        // label < 128 kept
            int lab = (int)sqrtf((float)c2);
            float2 f1 = t1[pos * PADC + kzl];
            float2 f2 = t2[pos * PADC + kzl];
            atomicAdd(&bs[wv][lab],          g * (f1.x * f2.x + f1.y * f2.y));
            atomicAdd(&bs[wv][NB + lab],     g * (f1.x * f1.x + f1.y * f1.y));
            atomicAdd(&bs[wv][2 * NB + lab], g * (f2.x * f2.x + f2.y * f2.y));
        }
    }
    __syncthreads();
    for (int i = t; i < 3 * NB; i += 256) {
        float v = bs[0][i] + bs[1][i] + bs[2][i] + bs[3][i];
        if (v != 0.f) atomicAdd(&bins[i], v);
    }
}

// ---------------------------------------------------------------------------
__global__ void zero_bins(float* bins)
{
    int t = blockIdx.x * blockDim.x + threadIdx.x;
    if (t < 2 * 3 * NB) bins[t] = 0.f;
}

__global__ void finalize(const float* __restrict__ binsAll, float* __restrict__ out)
{
    __shared__ float red[256];
    const int t = threadIdx.x;
    const int b = t >> 7, bin = t & 127;
    const float* bb = binsAll + b * 3 * NB;
    float num = bb[bin], d1 = bb[NB + bin], d2 = bb[2 * NB + bin];
    float fsc = num / sqrtf(d1 * d2 + 1e-8f);
    red[t] = fsc * fsc;
    __syncthreads();
    for (int s = 128; s > 0; s >>= 1) {
        if (t < s) red[t] += red[t + s];
        __syncthreads();
    }
    if (t == 0) out[0] = 1.f - red[0] / 256.f;
}

__global__ void ws_too_small(float* out) { out[0] = -1.0e9f; }

// ---------------------------------------------------------------------------
extern "C" void kernel_launch(void* const* d_in, const int* in_sizes, int n_in,
                              void* d_out, int out_size, void* d_ws, size_t ws_size,
                              hipStream_t stream)
{
    const float* ref  = (const float*)d_in[0];
    const float* pred = (const float*)d_in[1];
    float* out = (float*)d_out;

    const size_t volBytes = (size_t)HVOL * sizeof(float2) * 2;  // 134,217,728
    if (ws_size < volBytes + 4096) {
        ws_too_small<<<1, 1, 0, stream>>>(out);
        return;
    }
    float2* A1  = (float2*)d_ws;                 // F1z half-volume, 64 MB
    float2* A2  = A1 + HVOL;                     // F2z half-volume, 64 MB
    float* bins = (float*)((char*)d_ws + volBytes);  // [2][3][128]

    zero_bins<<<1, 1024, 0, stream>>>(bins);

    for (int b = 0; b < 2; ++b) {
        fftz_split<<<16384, 256, 0, stream>>>(ref + (size_t)b * VOL,
                                              pred + (size_t)b * VOL, A1, A2);
        fft_strided<<<2048, 256, 0, stream>>>(A1, 128, 32768LL, 7, 3);  // y-pass F1
        fft_strided<<<2048, 256, 0, stream>>>(A2, 128, 32768LL, 7, 3);  // y-pass F2
        fftx_reduce<<<4096, 256, 0, stream>>>(A1, A2, bins + b * 3 * NB);
    }
    finalize<<<1, 256, 0, stream>>>(bins, out);
}